// Round 4
// baseline (1244.424 us; speedup 1.0000x reference)
//
#include <hip/hip_runtime.h>

#define BB 128
#define TT 1024
#define II 100
#define HH 200

// ---------------------------------------------------------------------------
// Phase 1: xp[r][j] = b_ih[j] + b_hh[j] + sum_i x[r][i] * W_ih[j][i]
// (unchanged this round; known LDS-broadcast-bound, fix next round)
// ---------------------------------------------------------------------------
__global__ __launch_bounds__(256, 1) void rnn_xproj(
    const float* __restrict__ x, const float* __restrict__ Wih,
    const float* __restrict__ bih, const float* __restrict__ bhh,
    float* __restrict__ hid)
{
    __shared__ __align__(16) float xs[128 * II];  // 51.2 KB
    const int tid = threadIdx.x;
    const int j = tid;
    const int jl = (j < HH) ? j : (HH - 1);

    float4 w[25];
    const float4* wrow = (const float4*)(Wih + jl * II);
#pragma unroll
    for (int kk = 0; kk < 25; ++kk) w[kk] = wrow[kk];
    const float bias = bih[jl] + bhh[jl];

    const long long r0 = (long long)blockIdx.x * 128;
    const float4* src = (const float4*)(x + r0 * II);
    float4* dst = (float4*)xs;
    for (int p = tid; p < 128 * II / 4; p += 256) dst[p] = src[p];
    __syncthreads();

    for (int row = 0; row < 128; ++row) {
        float a0 = 0.f, a1 = 0.f, a2 = 0.f, a3 = 0.f;
        const float4* xr = (const float4*)(xs + row * II);
#pragma unroll
        for (int kk = 0; kk < 25; ++kk) {
            float4 v = xr[kk];
            a0 += w[kk].x * v.x; a1 += w[kk].y * v.y;
            a2 += w[kk].z * v.z; a3 += w[kk].w * v.w;
        }
        if (j < HH)
            hid[(r0 + row) * HH + j] = bias + ((a0 + a1) + (a2 + a3));
    }
}

// ---------------------------------------------------------------------------
// Phase 2: serial recurrence, readlane-harvest version.
// 128 blocks (1 per batch element) x 1024 threads = 16 waves:
//   wave = (k-quarter q = wv>>2) x (j-group = wv&3); j = 64*jgrp + lane.
// Thread holds 50 W_hh floats (k in [50q,50q+50)) -> ~70 VGPR, no spill.
// Per step: ONE distributed ds_read_b32 per wave (lane l holds h[50q+l]),
// then 50 x { v_readlane -> SGPR, v_fmac v,s,v }. Harvest rides the VALU
// (4 SIMDs parallel) instead of the serial per-CU LDS pipe.
// Partials combined through pbuf (3 quarters), 2 barriers/step.
// ---------------------------------------------------------------------------
__global__ __launch_bounds__(1024, 1) void rnn_recur(
    const float* __restrict__ Whh, float* __restrict__ hid)
{
    __shared__ float hbuf[256];      // h[0..199], pad zeros to 256
    __shared__ float pbuf[3][256];   // partial sums from quarters 1..3

    const int tid  = threadIdx.x;
    const int wv   = tid >> 6;
    const int lane = tid & 63;
    const int jgrp = wv & 3;
    const int q    = wv >> 2;          // k-quarter, 0..3
    const int j2   = jgrp * 64 + lane; // 0..255
    const bool jact = (j2 < HH);
    const int  jl   = jact ? j2 : (HH - 1);

    // W_hh[j][50q + kk], kk = 0..49 (8B-aligned float2 loads)
    float w[50];
    {
        const float2* wp = (const float2*)(Whh + jl * HH + 50 * q);
#pragma unroll
        for (int kk = 0; kk < 25; ++kk) {
            float2 v = wp[kk];
            w[2 * kk] = v.x; w[2 * kk + 1] = v.y;
        }
#pragma unroll
        for (int kk = 0; kk < 50; ++kk) asm volatile("" : "+v"(w[kk]));
    }

    if (tid < 256) hbuf[tid] = 0.f;
    __syncthreads();

    float* rowp = hid + (long long)blockIdx.x * TT * HH;
    float xpv = (q == 0 && jact) ? rowp[j2] : 0.f;  // xp for t=0

#pragma unroll 1
    for (int t = 0; t < TT; ++t) {
        // distributed read: lane l holds h[50q + l] (single ds_read_b32)
        float hA = hbuf[50 * q + lane];

        // prefetch next step's xp under the FMA loop
        float xpn = 0.f;
        if (q == 0 && jact && t + 1 < TT) xpn = rowp[HH + j2];

        float a0 = 0.f, a1 = 0.f, a2 = 0.f, a3 = 0.f;
#pragma unroll
        for (int kk = 0; kk < 48; kk += 4) {
            a0 += w[kk + 0] * __int_as_float(__builtin_amdgcn_readlane(__float_as_int(hA), kk + 0));
            a1 += w[kk + 1] * __int_as_float(__builtin_amdgcn_readlane(__float_as_int(hA), kk + 1));
            a2 += w[kk + 2] * __int_as_float(__builtin_amdgcn_readlane(__float_as_int(hA), kk + 2));
            a3 += w[kk + 3] * __int_as_float(__builtin_amdgcn_readlane(__float_as_int(hA), kk + 3));
        }
        a0 += w[48] * __int_as_float(__builtin_amdgcn_readlane(__float_as_int(hA), 48));
        a1 += w[49] * __int_as_float(__builtin_amdgcn_readlane(__float_as_int(hA), 49));
        float p = (a0 + a1) + (a2 + a3);

        if (q > 0) pbuf[q - 1][j2] = p;
        __syncthreads();                       // partials visible

        if (q == 0) {
            float s = p + pbuf[0][j2] + pbuf[1][j2] + pbuf[2][j2];
            float hv = fmaxf(xpv + s, 0.f);
            if (jact) { rowp[j2] = hv; hbuf[j2] = hv; }
        }
        __syncthreads();                       // new h visible
        xpv = xpn; rowp += HH;
    }
}

// ---------------------------------------------------------------------------
// Phase 3: o[r] = sum_j W_out[j]*h[r][j] + b_out. (unchanged)
// ---------------------------------------------------------------------------
__global__ __launch_bounds__(256) void rnn_out(
    const float* __restrict__ hid, const float* __restrict__ Wout,
    const float* __restrict__ bout, float* __restrict__ out)
{
    const int wave = threadIdx.x >> 6;
    const int lane = threadIdx.x & 63;

    float wv[4];
#pragma unroll
    for (int m = 0; m < 4; ++m) {
        int idx = lane + 64 * m;
        wv[m] = (idx < HH) ? Wout[idx] : 0.f;
    }
    const float bo = bout[0];

    const long long rbase = (long long)blockIdx.x * 64;
#pragma unroll 1
    for (int rr = wave; rr < 64; rr += 4) {
        const float* hr = hid + (rbase + rr) * HH;
        float p = 0.f;
#pragma unroll
        for (int m = 0; m < 4; ++m) {
            int idx = lane + 64 * m;
            if (idx < HH) p += wv[m] * hr[idx];
        }
#pragma unroll
        for (int off = 32; off; off >>= 1) p += __shfl_down(p, off, 64);
        if (lane == 0) out[rbase + rr] = p + bo;
    }
}

extern "C" void kernel_launch(void* const* d_in, const int* in_sizes, int n_in,
                              void* d_out, int out_size, void* d_ws, size_t ws_size,
                              hipStream_t stream)
{
    const float* x    = (const float*)d_in[0];  // [128,1024,100]
    const float* Wih  = (const float*)d_in[1];  // [200,100]
    const float* Whh  = (const float*)d_in[2];  // [200,200]
    const float* bih  = (const float*)d_in[3];  // [200]
    const float* bhh  = (const float*)d_in[4];  // [200]
    const float* Wout = (const float*)d_in[5];  // [1,200]
    const float* bout = (const float*)d_in[6];  // [1]

    float* out = (float*)d_out;                 // [128*1024] outputs first
    float* hid = out + (long long)BB * TT;      // [128*1024*200] hiddens

    rnn_xproj<<<(BB * TT) / 128, 256, 0, stream>>>(x, Wih, bih, bhh, hid);
    rnn_recur<<<BB, 1024, 0, stream>>>(Whh, hid);
    rnn_out<<<(BB * TT) / 64, 256, 0, stream>>>(hid, Wout, bout, out);
}

// Round 5
// 1181.071 us; speedup vs baseline: 1.0536x; 1.0536x over previous
//
#include <hip/hip_runtime.h>

#define BB 128
#define TT 1024
#define II 100
#define HH 200
#define MB 16          // batches per recurrence block -> 8 blocks
#define NTL 13         // ceil(200/16) j-tiles
#define KST 7          // ceil(200/32) k-steps
#define HSTR 232       // padded f16 row stride for H_lds (bank-friendly)

typedef _Float16 half8  __attribute__((ext_vector_type(8)));
typedef _Float16 half4v __attribute__((ext_vector_type(4)));
typedef float    f32x4  __attribute__((ext_vector_type(4)));

// ---------------------------------------------------------------------------
// Phase 1: xp[r][j] = b_ih[j] + b_hh[j] + sum_i x[r][i] * W_ih[j][i]
// (round-1 form, unchanged — isolate the recurrence experiment)
// ---------------------------------------------------------------------------
__global__ __launch_bounds__(256, 1) void rnn_xproj(
    const float* __restrict__ x, const float* __restrict__ Wih,
    const float* __restrict__ bih, const float* __restrict__ bhh,
    float* __restrict__ hid)
{
    __shared__ __align__(16) float xs[128 * II];  // 51.2 KB
    const int tid = threadIdx.x;
    const int j = tid;
    const int jl = (j < HH) ? j : (HH - 1);

    float4 w[25];
    const float4* wrow = (const float4*)(Wih + jl * II);
#pragma unroll
    for (int kk = 0; kk < 25; ++kk) w[kk] = wrow[kk];
    const float bias = bih[jl] + bhh[jl];

    const long long r0 = (long long)blockIdx.x * 128;
    const float4* src = (const float4*)(x + r0 * II);
    float4* dst = (float4*)xs;
    for (int p = tid; p < 128 * II / 4; p += 256) dst[p] = src[p];
    __syncthreads();

    for (int row = 0; row < 128; ++row) {
        float a0 = 0.f, a1 = 0.f, a2 = 0.f, a3 = 0.f;
        const float4* xr = (const float4*)(xs + row * II);
#pragma unroll
        for (int kk = 0; kk < 25; ++kk) {
            float4 v = xr[kk];
            a0 += w[kk].x * v.x; a1 += w[kk].y * v.y;
            a2 += w[kk].z * v.z; a3 += w[kk].w * v.w;
        }
        if (j < HH)
            hid[(r0 + row) * HH + j] = bias + ((a0 + a1) + (a2 + a3));
    }
}

// ---------------------------------------------------------------------------
// Phase 2: MFMA recurrence. 8 blocks x 256 threads (4 waves, 1 wave/SIMD via
// amdgpu_waves_per_eu(1,1) -> 512-VGPR budget, no occupancy-chasing spills).
// Per block: 16 batches. Per step: C^T[200j x 16m] = W_hh . H^T using
// mfma_f32_16x16x32_f16. Wave wv owns j-tiles nt = 4i+wv (zero-padded frags
// for nt >= 13 equalize MFMA load). W fragments: 112 VGPRs/thread, loaded
// ONCE (cvt chains are non-rematerializable). H double-buffered in LDS fp16.
// Fragment layouts (16x16x32): A lane l: row=l&15, k=8*(l>>4)+e;
// B lane l: col=l&15, k=8*(l>>4)+e; C lane l: col=l&15, row=4*(l>>4)+r.
// ---------------------------------------------------------------------------
__global__ __launch_bounds__(256, 1) __attribute__((amdgpu_waves_per_eu(1, 1)))
void rnn_recur(const float* __restrict__ Whh, float* __restrict__ hid)
{
    __shared__ _Float16 hl[2][MB][HSTR];   // 14.8 KB double-buffered H (fp16)

    const int tid = threadIdx.x;
    const int wv  = tid >> 6;
    const int l   = tid & 63;
    const int m   = l & 15;     // batch index within group (B-col / C-col)
    const int kq  = l >> 4;     // k-subblock 0..3

    // ---- one-time: W_hh -> per-wave A-fragments in registers ----
    half8 wf[4][KST];
#pragma unroll
    for (int i = 0; i < 4; ++i) {
        const int nt = 4 * i + wv;
        const bool v = (nt < NTL);
        int j = 16 * nt + m; if (j > HH - 1) j = HH - 1;   // clamp (rows j>=200 masked later)
#pragma unroll
        for (int ks = 0; ks < KST; ++ks) {
            const int k0 = 32 * ks + 8 * kq;
            half8 f;
#pragma unroll
            for (int e = 0; e < 8; ++e) f[e] = (_Float16)0.f;
            if (v && k0 < HH) {   // k0 multiple of 8 and <200 => k0<=192 => 8 floats in-bounds
                const float4 lo = *(const float4*)(Whh + j * HH + k0);
                const float4 hi = *(const float4*)(Whh + j * HH + k0 + 4);
                f[0] = (_Float16)lo.x; f[1] = (_Float16)lo.y;
                f[2] = (_Float16)lo.z; f[3] = (_Float16)lo.w;
                f[4] = (_Float16)hi.x; f[5] = (_Float16)hi.y;
                f[6] = (_Float16)hi.z; f[7] = (_Float16)hi.w;
            }
            wf[i][ks] = f;
        }
    }

    // per-i epilogue geometry
    int  j0a[4]; bool stv[4];
#pragma unroll
    for (int i = 0; i < 4; ++i) {
        const int nt = 4 * i + wv;
        j0a[i] = 16 * nt + 4 * kq;
        stv[i] = (nt < NTL) && (j0a[i] < HH);   // j0 mult of 4, so j0+3<200 too
    }

    // zero both H buffers (incl. k-padding columns)
    {
        int* zp = (int*)hl;
        for (int p = tid; p < (int)(sizeof(hl) / 4); p += 256) zp[p] = 0;
    }
    __syncthreads();

    const long long TTHH = (long long)TT * HH;
    float* mybase = hid + (long long)blockIdx.x * MB * TTHH + (long long)m * TTHH;

    // prologue: xp for t=0
    float4 xpv[4];
#pragma unroll
    for (int i = 0; i < 4; ++i)
        xpv[i] = stv[i] ? *(const float4*)(mybase + j0a[i])
                        : make_float4(0.f, 0.f, 0.f, 0.f);

    int cur = 0;
#pragma unroll 1
    for (int t = 0; t < TT; ++t) {
        // prefetch xp(t+1) — lands under this step's MFMAs / barrier
        float4 xpn[4];
        const bool pf = (t + 1 < TT);
#pragma unroll
        for (int i = 0; i < 4; ++i)
            xpn[i] = (pf && stv[i])
                   ? *(const float4*)(mybase + (long long)(t + 1) * HH + j0a[i])
                   : make_float4(0.f, 0.f, 0.f, 0.f);

        // B-fragments: H^T slices from LDS (lane: col=m, k=32*ks+8*kq+e)
        half8 bf[KST];
        const _Float16* hb = &hl[cur][m][0];
#pragma unroll
        for (int ks = 0; ks < KST; ++ks)
            bf[ks] = *(const half8*)(hb + 32 * ks + 8 * kq);

        // MFMA accumulate: acc[i] = sum_ks W(nt,ks) x H(ks)
        f32x4 acc[4];
#pragma unroll
        for (int i = 0; i < 4; ++i) acc[i] = (f32x4){0.f, 0.f, 0.f, 0.f};
#pragma unroll
        for (int ks = 0; ks < KST; ++ks) {
#pragma unroll
            for (int i = 0; i < 4; ++i)
                acc[i] = __builtin_amdgcn_mfma_f32_16x16x32_f16(
                    wf[i][ks], bf[ks], acc[i], 0, 0, 0);
        }

        // epilogue: h = relu(xp + acc); store fp32 to hid, fp16 to next H buf
#pragma unroll
        for (int i = 0; i < 4; ++i) {
            if (!stv[i]) continue;
            const float h0 = fmaxf(acc[i][0] + xpv[i].x, 0.f);
            const float h1 = fmaxf(acc[i][1] + xpv[i].y, 0.f);
            const float h2 = fmaxf(acc[i][2] + xpv[i].z, 0.f);
            const float h3 = fmaxf(acc[i][3] + xpv[i].w, 0.f);
            *(float4*)(mybase + (long long)t * HH + j0a[i]) =
                make_float4(h0, h1, h2, h3);
            half4v pk = {(_Float16)h0, (_Float16)h1, (_Float16)h2, (_Float16)h3};
            *(half4v*)&hl[cur ^ 1][m][j0a[i]] = pk;
        }

        __syncthreads();   // H(t+1) visible; also orders WAR on hl[cur]
        cur ^= 1;
#pragma unroll
        for (int i = 0; i < 4; ++i) xpv[i] = xpn[i];
    }
}

// ---------------------------------------------------------------------------
// Phase 3: o[r] = sum_j W_out[j]*h[r][j] + b_out. (unchanged)
// ---------------------------------------------------------------------------
__global__ __launch_bounds__(256) void rnn_out(
    const float* __restrict__ hid, const float* __restrict__ Wout,
    const float* __restrict__ bout, float* __restrict__ out)
{
    const int wave = threadIdx.x >> 6;
    const int lane = threadIdx.x & 63;

    float wv[4];
#pragma unroll
    for (int mi = 0; mi < 4; ++mi) {
        int idx = lane + 64 * mi;
        wv[mi] = (idx < HH) ? Wout[idx] : 0.f;
    }
    const float bo = bout[0];

    const long long rbase = (long long)blockIdx.x * 64;
#pragma unroll 1
    for (int rr = wave; rr < 64; rr += 4) {
        const float* hr = hid + (rbase + rr) * HH;
        float p = 0.f;
#pragma unroll
        for (int mi = 0; mi < 4; ++mi) {
            int idx = lane + 64 * mi;
            if (idx < HH) p += wv[mi] * hr[idx];
        }
#pragma unroll
        for (int off = 32; off; off >>= 1) p += __shfl_down(p, off, 64);
        if (lane == 0) out[rbase + rr] = p + bo;
    }
}

extern "C" void kernel_launch(void* const* d_in, const int* in_sizes, int n_in,
                              void* d_out, int out_size, void* d_ws, size_t ws_size,
                              hipStream_t stream)
{
    const float* x    = (const float*)d_in[0];  // [128,1024,100]
    const float* Wih  = (const float*)d_in[1];  // [200,100]
    const float* Whh  = (const float*)d_in[2];  // [200,200]
    const float* bih  = (const float*)d_in[3];  // [200]
    const float* bhh  = (const float*)d_in[4];  // [200]
    const float* Wout = (const float*)d_in[5];  // [1,200]
    const float* bout = (const float*)d_in[6];  // [1]

    float* out = (float*)d_out;                 // [128*1024] outputs first
    float* hid = out + (long long)BB * TT;      // [128*1024*200] hiddens

    rnn_xproj<<<(BB * TT) / 128, 256, 0, stream>>>(x, Wih, bih, bhh, hid);
    rnn_recur<<<BB / MB, 256, 0, stream>>>(Whh, hid);
    rnn_out<<<(BB * TT) / 64, 256, 0, stream>>>(hid, Wout, bout, out);
}